// Round 4
// baseline (738.039 us; speedup 1.0000x reference)
//
#include <hip/hip_runtime.h>

#define N_NODES 50000
#define N_EDGES 600000
#define HDIM 128
#define KEIG 32
#define FEAT9 1152  // 9*H

typedef short s8v __attribute__((ext_vector_type(8)));
typedef __bf16 bf8v __attribute__((ext_vector_type(8)));
typedef float f4v __attribute__((ext_vector_type(4)));

__device__ __forceinline__ unsigned short f2bf(float f) {
    unsigned u = __float_as_uint(f);
    u += 0x7fff + ((u >> 16) & 1);   // round to nearest even
    return (unsigned short)(u >> 16);
}
__device__ __forceinline__ float bf2f(unsigned short h) {
    return __uint_as_float(((unsigned)h) << 16);
}
__device__ __forceinline__ unsigned pack2(float a, float b) {
    return (unsigned)f2bf(a) | ((unsigned)f2bf(b) << 16);
}
__device__ __forceinline__ bf8v as_bf(s8v v) { return __builtin_bit_cast(bf8v, v); }

// ============ Phase 1: W pre-swizzle | edge histogram | coeff partials ======
// prep: B-frag (16x16x32): lane holds B[k=(lane>>4)*8+j][n=lane&15], j=0..7.
// Gather-read form (coalesced writes) — the R3 scatter form regressed.
__global__ __launch_bounds__(256) void k_phase1(
    const float* __restrict__ Wp, const float* __restrict__ Wl,
    unsigned short* __restrict__ Wswz, unsigned short* __restrict__ WlB,
    const int* __restrict__ dst, int* __restrict__ cnt,
    const float* __restrict__ node_fts, const float* __restrict__ deg,
    const float* __restrict__ eig, float* __restrict__ partials) {
    int b = blockIdx.x, t = threadIdx.x;
    if (b < 640) {                              // --- prep (163840 threads)
        int tid = b * 256 + t;
        if (tid < 147456) {                     // Wswz: 36*8*64*8
            int j = tid & 7, lane = (tid >> 3) & 63, tn = (tid >> 9) & 7, s = tid >> 12;
            int k = s * 32 + (lane >> 4) * 8 + j;
            int c = tn * 16 + (lane & 15);
            Wswz[tid] = f2bf(Wp[(size_t)k * HDIM + c]);
        } else {                                // WlB: 4*8*64*8
            int t2 = tid - 147456;
            int j = t2 & 7, lane = (t2 >> 3) & 63, tn = (t2 >> 9) & 7, s = t2 >> 12;
            int k = s * 32 + (lane >> 4) * 8 + j;
            int c = tn * 16 + (lane & 15);
            WlB[t2] = f2bf(Wl[(size_t)(128 + k) * HDIM + c]);
        }
    } else if (b < 2984) {                      // --- histogram
        int e = (b - 640) * 256 + t;
        if (e < N_EDGES) atomicAdd(&cnt[dst[e]], 1);
    } else {                                    // --- coeff partials (782 blocks)
        int bb = b - 2984;
        int h = t & 127, half = t >> 7;
        int base = bb * 64 + half * 32;
        float acc[KEIG];
#pragma unroll
        for (int k = 0; k < KEIG; k++) acc[k] = 0.f;
        int lim = N_NODES - base; if (lim > 32) lim = 32;
        for (int r = 0; r < lim; r++) {
            int n = base + r;
            float v = deg[n] * node_fts[(size_t)n * HDIM + h];
            const float4* e4 = (const float4*)(eig + (size_t)n * KEIG);
#pragma unroll
            for (int q = 0; q < 8; q++) {
                float4 e = e4[q];
                acc[q * 4 + 0] += e.x * v;
                acc[q * 4 + 1] += e.y * v;
                acc[q * 4 + 2] += e.z * v;
                acc[q * 4 + 3] += e.w * v;
            }
        }
#pragma unroll
        for (int k = 0; k < KEIG; k++)
            partials[(size_t)(bb * 2 + half) * 4096 + k * 128 + h] = acc[k];
    }
}

// ============ Phase 2: coeff reduce | per-chip count sums ===================
__global__ __launch_bounds__(256) void k_phase2(
    const float* __restrict__ partials, float* __restrict__ coeff,
    const int* __restrict__ cnt, int* __restrict__ bsum) {
    int b = blockIdx.x, t = threadIdx.x;
    if (b < 128) {                              // --- credu: 16 col-grp x 8 chunks
        int i = (b & 15) * 256 + t;             // 0..4095
        int chunk = b >> 4;
        int p0 = chunk * 196;
        int p1 = p0 + 196; if (p1 > 1564) p1 = 1564;
        float s = 0.f;
        for (int p = p0; p < p1; p++) s += partials[(size_t)p * 4096 + i];
        atomicAdd(&coeff[i], s);
    } else {                                    // --- scan_part (50 blocks)
        __shared__ int sm[256];
        int bb = b - 128;
        int base = bb * 1024 + t * 4;
        int s = 0;
#pragma unroll
        for (int j = 0; j < 4; j++) { int i = base + j; if (i < N_NODES) s += cnt[i]; }
        sm[t] = s;
        __syncthreads();
        for (int d = 128; d > 0; d >>= 1) {
            if (t < d) sm[t] += sm[t + d];
            __syncthreads();
        }
        if (t == 0) bsum[bb] = sm[0];
    }
}

// ============ Phase 3: block-offset scan | coeff2 = coeff * exp-scale =======
__global__ __launch_bounds__(256) void k_phase3(
    const int* __restrict__ bsum, int* __restrict__ boff,
    const float* __restrict__ coeff, const float* __restrict__ lam,
    const float* __restrict__ dt, float* __restrict__ coeff2) {
    int b = blockIdx.x, t = threadIdx.x;
    if (b == 0) {                               // --- scan_mid (wave 0 only)
        if (t < 64) {
            int v = (t < 50) ? bsum[t] : 0;
            int x = v;
#pragma unroll
            for (int d = 1; d < 64; d <<= 1) {
                int y = __shfl_up(x, d, 64);
                if (t >= d) x += y;
            }
            boff[t] = x - v;  // exclusive
        }
    } else {                                    // --- scale (16 blocks)
        int i = (b - 1) * 256 + t;              // 0..4095
        int k = i >> 7, h = i & 127;
        float tt = log1pf(expf(dt[h]));
        coeff2[i] = coeff[i] * expf(-lam[k] * tt);
    }
}

// ============ Phase 4: CSR offsets | C2A = coeff2 @ WlA =====================
__global__ __launch_bounds__(256) void k_phase4(
    const int* __restrict__ cnt, const int* __restrict__ boff,
    int* __restrict__ offsets, int* __restrict__ cursor,
    const float* __restrict__ coeff2, const float* __restrict__ Wl,
    float* __restrict__ C2A) {
    int b = blockIdx.x, t = threadIdx.x;
    if (b < 50) {                               // --- scan_out
        __shared__ int sm[256];
        int base = b * 1024 + t * 4;
        int c[4]; int ts = 0;
#pragma unroll
        for (int j = 0; j < 4; j++) { int i = base + j; c[j] = (i < N_NODES) ? cnt[i] : 0; ts += c[j]; }
        sm[t] = ts;
        __syncthreads();
        for (int d = 1; d < 256; d <<= 1) {
            int add = (t >= d) ? sm[t - d] : 0;
            __syncthreads();
            sm[t] += add;
            __syncthreads();
        }
        int run = boff[b] + sm[t] - ts;
#pragma unroll
        for (int j = 0; j < 4; j++) {
            int i = base + j;
            if (i < N_NODES) { offsets[i] = run; cursor[i] = run; run += c[j]; }
        }
        if (b == 0 && t == 0) offsets[N_NODES] = N_EDGES;
    } else {                                    // --- C2A (16 blocks, 4096 outs)
        int idx = (b - 50) * 256 + t;
        int k = idx >> 7, c = idx & 127;
        float s = 0.f;
        for (int j = 0; j < 128; j++) s += coeff2[k * 128 + j] * Wl[(size_t)j * HDIM + c];
        C2A[idx] = s;
    }
}

// ============ Phase 5: edge bucket | diffuse (x -> feats, y0 = x@WlA) =======
__global__ __launch_bounds__(256) void k_phase5(
    const int* __restrict__ ei, const float* __restrict__ F,
    int* __restrict__ cursor, int* __restrict__ ssrc, float* __restrict__ sF,
    const float* __restrict__ eig, const float* __restrict__ coeff2,
    const float* __restrict__ C2A, unsigned short* __restrict__ feats,
    float* __restrict__ y0) {
    int b = blockIdx.x, t = threadIdx.x;
    if (b < 2344) {                             // --- bucket
        int e = b * 256 + t;
        if (e < N_EDGES) {
            int d = ei[N_EDGES + e];
            int p = atomicAdd(&cursor[d], 1);
            ssrc[p] = ei[e];
            sF[p] = F[e];
        }
    } else {                                    // --- diffuse (782 blocks)
        __shared__ float c2[KEIG * HDIM];
        __shared__ float cA[KEIG * HDIM];
        int bb = b - 2344;
        int h = t & 127, half = t >> 7;
#pragma unroll
        for (int j = half * 16; j < half * 16 + 16; j++) {
            c2[j * 128 + h] = coeff2[j * 128 + h];
            cA[j * 128 + h] = C2A[j * 128 + h];
        }
        __syncthreads();
        int base = bb * 64 + half * 32;
        for (int r = 0; r < 32; r++) {
            int n = base + r;
            if (n >= N_NODES) break;
            const float4* e4 = (const float4*)(eig + (size_t)n * KEIG);
            float xs = 0.f, ys = 0.f;
#pragma unroll
            for (int q = 0; q < 8; q++) {
                float4 e = e4[q];
                int k0 = q * 4;
                xs += e.x * c2[(k0 + 0) * 128 + h] + e.y * c2[(k0 + 1) * 128 + h]
                    + e.z * c2[(k0 + 2) * 128 + h] + e.w * c2[(k0 + 3) * 128 + h];
                ys += e.x * cA[(k0 + 0) * 128 + h] + e.y * cA[(k0 + 1) * 128 + h]
                    + e.z * cA[(k0 + 2) * 128 + h] + e.w * cA[(k0 + 3) * 128 + h];
            }
            feats[(size_t)n * FEAT9 + h] = f2bf(xs);
            y0[(size_t)n * HDIM + h] = ys;
        }
    }
}

// ============ per-node aggregation -> feats[:, 128:1152] ====================
__global__ __launch_bounds__(256) void k_agg(
    unsigned short* __restrict__ feats, const int* __restrict__ offsets,
    const int* __restrict__ ssrc, const float* __restrict__ sF,
    const float* __restrict__ degv, const float* __restrict__ Fdig) {
    int n = blockIdx.x * 4 + (threadIdx.x >> 6);
    int t = threadIdx.x & 63;  // channels 2t and 2t+1
    if (n >= N_NODES) return;
    int beg = offsets[n], end = offsets[n + 1];
    const unsigned* fx = (const unsigned*)feats;  // row pitch = 576 uints
    float s0 = 0.f, s1 = 0.f, w0 = 0.f, w1 = 0.f, f0 = 0.f, f1 = 0.f;
    float m0 = -3.4e38f, m1 = -3.4e38f, wS = 0.f;
    int e = beg;
    for (; e + 3 < end; e += 4) {
        int  sa = ssrc[e], sb = ssrc[e + 1], sc = ssrc[e + 2], sd = ssrc[e + 3];
        float Fa = sF[e], Fb = sF[e + 1], Fc = sF[e + 2], Fd = sF[e + 3];
        unsigned va = fx[(size_t)sa * 576 + t];
        unsigned vb = fx[(size_t)sb * 576 + t];
        unsigned vc = fx[(size_t)sc * 576 + t];
        unsigned vd = fx[(size_t)sd * 576 + t];
        float wa = fabsf(Fa), wb = fabsf(Fb), wc = fabsf(Fc), wd = fabsf(Fd);
        wS += wa + wb + wc + wd;
        float a0 = bf2f(va & 0xffff), a1 = bf2f(va >> 16);
        float b0 = bf2f(vb & 0xffff), b1 = bf2f(vb >> 16);
        float c0 = bf2f(vc & 0xffff), c1 = bf2f(vc >> 16);
        float d0 = bf2f(vd & 0xffff), d1 = bf2f(vd >> 16);
        s0 += a0 + b0 + c0 + d0;  s1 += a1 + b1 + c1 + d1;
        m0 = fmaxf(fmaxf(fmaxf(m0, a0), fmaxf(b0, c0)), d0);
        m1 = fmaxf(fmaxf(fmaxf(m1, a1), fmaxf(b1, c1)), d1);
        w0 += wa * a0 + wb * b0 + wc * c0 + wd * d0;
        w1 += wa * a1 + wb * b1 + wc * c1 + wd * d1;
        f0 += Fa * a0 + Fb * b0 + Fc * c0 + Fd * d0;
        f1 += Fa * a1 + Fb * b1 + Fc * c1 + Fd * d1;
    }
    for (; e < end; e++) {
        int sa = ssrc[e];
        float Fa = sF[e], wa = fabsf(Fa);
        unsigned va = fx[(size_t)sa * 576 + t];
        float a0 = bf2f(va & 0xffff), a1 = bf2f(va >> 16);
        s0 += a0; s1 += a1;
        m0 = fmaxf(m0, a0); m1 = fmaxf(m1, a1);
        w0 += wa * a0; w1 += wa * a1;
        f0 += Fa * a0; f1 += Fa * a1;
        wS += wa;
    }
    float dv = degv[n];
    float inv = 1.f / dv;
    float me0 = s0 * inv, me1 = s1 * inv;
    float mx0 = (end > beg) ? m0 : 0.f, mx1 = (end > beg) ? m1 : 0.f;
    float wi = 1.f / (wS + 1e-8f);
    float da0 = w0 * wi, da1 = w1 * wi;
    unsigned vx = fx[(size_t)n * 576 + t];
    float Fg = Fdig[n];
    float dd0 = f0 - Fg * bf2f(vx & 0xffff);
    float dd1 = f1 - Fg * bf2f(vx >> 16);
    float amp = log1pf(dv) / 2.5649493574615367f;  // log(13)
    unsigned* fr = (unsigned*)(feats + (size_t)n * FEAT9) + t;
    fr[64]  = pack2(me0, me1);
    fr[128] = pack2(mx0, mx1);
    fr[192] = pack2(da0, da1);
    fr[256] = pack2(dd0, dd1);
    fr[320] = pack2(me0 * amp, me1 * amp);
    fr[384] = pack2(mx0 * amp, mx1 * amp);
    fr[448] = pack2(da0 * amp, da1 * amp);
    fr[512] = pack2(dd0 * amp, dd1 * amp);
}

// ============ fused MFMA GEMM ==============================================
// 64 rows/block (782 blocks, balanced ~3/CU), 128 thr = 2 waves x 2 M-tiles.
// Main loop: GEMM1 only (acc1 live, 64 VGPR), direct-global A w/ reg prefetch,
// zero barriers. Then h->LDS (one barrier pair) -> GEMM2b. x@WlA arrives as
// precomputed y0 (added in epilogue).
__global__ __launch_bounds__(128, 3) void k_gemm(
    const unsigned short* __restrict__ feats, const unsigned short* __restrict__ Wswz,
    const unsigned short* __restrict__ WlB,
    const float* __restrict__ b_post, const float* __restrict__ b_last,
    const float* __restrict__ norm_n, const float* __restrict__ node_fts,
    const float* __restrict__ y0, float* __restrict__ out) {
    __shared__ unsigned short Hs[64 * 136];  // 64 rows x 128 cols h, +8 pad
    int tid = threadIdx.x;
    int wave = tid >> 6, lane = tid & 63;
    int m16 = lane & 15, quad = lane >> 4;
    int r0 = blockIdx.x * 64;
    int wr = r0 + wave * 32;

    int ra = wr + m16;      if (ra > N_NODES - 1) ra = N_NODES - 1;
    int rb = wr + 16 + m16; if (rb > N_NODES - 1) rb = N_NODES - 1;
    const unsigned short* gA0 = feats + (size_t)ra * FEAT9 + quad * 8;
    const unsigned short* gA1 = feats + (size_t)rb * FEAT9 + quad * 8;

    f4v acc1[2][8];
#pragma unroll
    for (int t = 0; t < 2; t++)
#pragma unroll
        for (int nt = 0; nt < 8; nt++) acc1[t][nt] = (f4v)(0.f);

    s8v a0 = *(const s8v*)gA0;
    s8v a1 = *(const s8v*)gA1;
    for (int s = 0; s < 36; s++) {
        int sn = (s < 35) ? s + 1 : 35;
        s8v n0 = *(const s8v*)(gA0 + sn * 32);
        s8v n1 = *(const s8v*)(gA1 + sn * 32);
        const s8v* bp = (const s8v*)Wswz + (size_t)(s * 8) * 64 + lane;
#pragma unroll
        for (int nt = 0; nt < 8; nt++) {
            s8v b = bp[nt * 64];
            acc1[0][nt] = __builtin_amdgcn_mfma_f32_16x16x32_bf16(as_bf(a0), as_bf(b), acc1[0][nt], 0, 0, 0);
            acc1[1][nt] = __builtin_amdgcn_mfma_f32_16x16x32_bf16(as_bf(a1), as_bf(b), acc1[1][nt], 0, 0, 0);
        }
        a0 = n0; a1 = n1;
    }

    // epilogue1: h = relu(acc1 + b_post) * norm_n -> Hs (bf16, A-layout source)
    float nrm[2][4];
#pragma unroll
    for (int t = 0; t < 2; t++)
#pragma unroll
        for (int r = 0; r < 4; r++) {
            int gr = wr + t * 16 + quad * 4 + r;
            if (gr > N_NODES - 1) gr = N_NODES - 1;
            nrm[t][r] = norm_n[gr];
        }
#pragma unroll
    for (int t = 0; t < 2; t++)
#pragma unroll
        for (int nt = 0; nt < 8; nt++) {
            float bb = b_post[nt * 16 + m16];
            int col = nt * 16 + m16;
#pragma unroll
            for (int r = 0; r < 4; r++) {
                float v = acc1[t][nt][r] + bb;
                v = v > 0.f ? v : 0.f;
                v *= nrm[t][r];
                int lrow = wave * 32 + t * 16 + quad * 4 + r;
                Hs[lrow * 136 + col] = f2bf(v);
            }
        }
    __syncthreads();

    // GEMM2b: h @ WlB (4 k-steps of 32)
    f4v acc2[2][8];
#pragma unroll
    for (int t = 0; t < 2; t++)
#pragma unroll
        for (int nt = 0; nt < 8; nt++) acc2[t][nt] = (f4v)(0.f);
#pragma unroll
    for (int s = 0; s < 4; s++) {
        s8v ha0 = *(const s8v*)(Hs + (wave * 32 + m16) * 136 + s * 32 + quad * 8);
        s8v ha1 = *(const s8v*)(Hs + (wave * 32 + 16 + m16) * 136 + s * 32 + quad * 8);
        const s8v* bp = (const s8v*)WlB + (size_t)(s * 8) * 64 + lane;
#pragma unroll
        for (int nt = 0; nt < 8; nt++) {
            s8v b = bp[nt * 64];
            acc2[0][nt] = __builtin_amdgcn_mfma_f32_16x16x32_bf16(as_bf(ha0), as_bf(b), acc2[0][nt], 0, 0, 0);
            acc2[1][nt] = __builtin_amdgcn_mfma_f32_16x16x32_bf16(as_bf(ha1), as_bf(b), acc2[1][nt], 0, 0, 0);
        }
    }

    // epilogue2: out = acc2 + b_last + y0 + node_fts
#pragma unroll
    for (int t = 0; t < 2; t++)
#pragma unroll
        for (int nt = 0; nt < 8; nt++) {
            int col = nt * 16 + m16;
            float bl = b_last[col];
#pragma unroll
            for (int r = 0; r < 4; r++) {
                int gr = wr + t * 16 + quad * 4 + r;
                if (gr < N_NODES) {
                    size_t o = (size_t)gr * HDIM + col;
                    out[o] = acc2[t][nt][r] + bl + y0[o] + node_fts[o];
                }
            }
        }
}

extern "C" void kernel_launch(void* const* d_in, const int* in_sizes, int n_in,
                              void* d_out, int out_size, void* d_ws, size_t ws_size,
                              hipStream_t stream) {
    const float* node_fts = (const float*)d_in[0];
    const int*   eidx     = (const int*)d_in[2];
    const float* Fnorm    = (const float*)d_in[3];
    const float* Fdig     = (const float*)d_in[4];
    const float* degv     = (const float*)d_in[5];
    const float* lam      = (const float*)d_in[8];
    const float* eig      = (const float*)d_in[9];
    const float* norm_n   = (const float*)d_in[11];
    const float* dtimes   = (const float*)d_in[13];
    const float* Wp       = (const float*)d_in[14];
    const float* bp       = (const float*)d_in[15];
    const float* Wl       = (const float*)d_in[16];
    const float* bl       = (const float*)d_in[17];
    float* out = (float*)d_out;

    char* w = (char*)d_ws;
    size_t off = 0;
    auto carve = [&](size_t bytes) -> char* {
        char* p = w + off;
        off = (off + bytes + 255) & ~(size_t)255;
        return p;
    };
    unsigned short* feats = (unsigned short*)carve((size_t)N_NODES * FEAT9 * 2);
    unsigned short* Wswz  = (unsigned short*)carve((size_t)147456 * 2);
    unsigned short* WlB   = (unsigned short*)carve((size_t)16384 * 2);
    float* partials = (float*)carve((size_t)1564 * 4096 * 4);
    float* coeff  = (float*)carve(4096 * 4);
    float* coeff2 = (float*)carve(4096 * 4);
    float* C2A    = (float*)carve(4096 * 4);
    float* y0     = (float*)carve((size_t)N_NODES * HDIM * 4);
    int* cnt      = (int*)carve((size_t)N_NODES * 4);
    int* offsets  = (int*)carve(((size_t)N_NODES + 1) * 4);
    int* cursor   = (int*)carve((size_t)N_NODES * 4);
    int* ssrc     = (int*)carve((size_t)N_EDGES * 4);
    float* sF     = (float*)carve((size_t)N_EDGES * 4);
    int* bsum     = (int*)carve(64 * 4);
    int* boff     = (int*)carve(64 * 4);

    hipMemsetAsync(coeff, 0, 4096 * 4, stream);
    hipMemsetAsync(cnt, 0, (size_t)N_NODES * 4, stream);

    k_phase1<<<3766, 256, 0, stream>>>(Wp, Wl, Wswz, WlB, eidx + N_EDGES, cnt,
                                       node_fts, degv, eig, partials);
    k_phase2<<<178, 256, 0, stream>>>(partials, coeff, cnt, bsum);
    k_phase3<<<17, 256, 0, stream>>>(bsum, boff, coeff, lam, dtimes, coeff2);
    k_phase4<<<66, 256, 0, stream>>>(cnt, boff, offsets, cursor, coeff2, Wl, C2A);
    k_phase5<<<3126, 256, 0, stream>>>(eidx, Fnorm, cursor, ssrc, sF, eig, coeff2,
                                       C2A, feats, y0);
    k_agg<<<(N_NODES + 3) / 4, 256, 0, stream>>>(feats, offsets, ssrc, sF, degv, Fdig);
    k_gemm<<<(N_NODES + 63) / 64, 128, 0, stream>>>(feats, Wswz, WlB, bp, bl, norm_n,
                                                    node_fts, y0, out);
}